// Round 10
// baseline (1689.496 us; speedup 1.0000x reference)
//
#include <hip/hip_runtime.h>
#include <float.h>

#define Bz   4
#define Cz   128
#define Nz   8192
#define Kz   20
#define OUTz 128

typedef float f16v __attribute__((ext_vector_type(16)));

// ---------------------------------------------------------------------------
// Kernel 1: xx[b*N+n] = sum_c x[b][c][n]^2   (unchanged)
// ---------------------------------------------------------------------------
__global__ __launch_bounds__(256) void xx_kernel(const float* __restrict__ x,
                                                 float* __restrict__ xx) {
    int t = blockIdx.x * 256 + threadIdx.x;          // 0 .. B*N-1
    int b = t >> 13;
    int n = t & (Nz - 1);
    const float* xp = x + (size_t)b * Cz * Nz + n;
    float s = 0.f;
#pragma unroll 8
    for (int c = 0; c < Cz; ++c) {
        float v = xp[(size_t)c * Nz];
        s = fmaf(v, v, s);
    }
    xx[t] = s;
}

// ---------------------------------------------------------------------------
// Kernel 2: pairwise-score GEMM + per-row top-20; SGPR-A / global-B / no-LDS
// inner loop.
// Grid (N/32, B) = 1024 blocks, block 256. Block = 32 queries (wave-uniform
// -> A loaded via explicit inline-asm s_load_dwordx16 into SGPRs, double-
// buffered; SMEM returns out-of-order so only lgkmcnt(0) waits are used,
// placed BEFORE the next issue so each c-step's 32 FMAs cover the next
// s_load's latency). Per pass: thread owns key kp*256+tid; B values loaded
// per-lane coalesced from global (L2-resident, 8-c-group double buffer).
// Inner loop: zero LDS, zero barriers; per c-step = 32 v_fmac(s,v,v).
// Selection per pass (256 keys): 4 sub-phases of 64; wave sp writes its
// lanes' score columns to an 8KB rotated sc tile; owner lanes (8/wave)
// scan+extract exactly as rounds 7-9 (ascending pass -> sub-phase -> j,
// strict >, live-wv recheck) -> identical final sets.
// Per-pair fp32 chain (ascending c, single fmaf(A,B,acc), 2*acc-xx)
// IDENTICAL to rounds 1-9 -> bit-identical output.
// ---------------------------------------------------------------------------
__global__ __launch_bounds__(256) void knn_kernel(const float* __restrict__ x,
                                                  const float* __restrict__ xxg,
                                                  int* __restrict__ idxout) {
    const int b  = blockIdx.y;
    const int q0 = blockIdx.x * 32;

    __shared__ float sc[32 * 64];   // 8KB score tile (selection only)

    const int tid  = threadIdx.x;
    const int lane = tid & 63;
    const int wid  = tid >> 6;

    const float* xb = x + (size_t)b * Cz * Nz;
    const float* aq = xb + q0;      // A base: row c at aq + c*Nz (uniform)

    // top-20 state: owners = lanes 0..7 of each wave; row orow = wid*8+lane
    float tv[Kz];
    int   ti[Kz];
#pragma unroll
    for (int s = 0; s < Kz; ++s) { tv[s] = -FLT_MAX; ti[s] = 0; }
    float wv = -FLT_MAX;
    int wslot = 0;
    const int orow = wid * 8 + lane;           // owner row (lane<8)
    const int srow = wid * 8 + (lane & 7);     // scanned row (all lanes)
    const int part = lane >> 3;                // 8-col part (0..7)

    // SGPR A double buffer (2 x 32 floats)
    f16v sA0, sB0, sA1, sB1;
    // prologue: c=0 into set0 (each pass's last CSTEP re-issues c=0 wrapped)
    asm volatile("s_load_dwordx16 %0, %2, 0x0\n\t"
                 "s_load_dwordx16 %1, %2, 0x40"
                 : "=&s"(sA0), "=&s"(sB0) : "s"(aq));

// one c-step: wait current A set, issue next c's A loads, 32 FMAs.
#define CSTEP(cA, cB, nA, nB, vbv, cidx)                                      \
    {                                                                         \
        const int cn_ = ((cidx) + 1) & 127;                                   \
        const float* apn_ = aq + ((size_t)cn_ << 13);                         \
        asm volatile("s_waitcnt lgkmcnt(0)" : "+s"(cA), "+s"(cB));            \
        asm volatile("s_load_dwordx16 %0, %2, 0x0\n\t"                        \
                     "s_load_dwordx16 %1, %2, 0x40"                           \
                     : "=&s"(nA), "=&s"(nB) : "s"(apn_));                     \
        const float vv_ = (vbv);                                              \
        _Pragma("unroll")                                                     \
        for (int q = 0; q < 16; ++q) acc[q] = fmaf(cA[q], vv_, acc[q]);       \
        _Pragma("unroll")                                                     \
        for (int q = 0; q < 16; ++q) acc[16 + q] = fmaf(cB[q], vv_, acc[16 + q]); \
    }

// 8 consecutive c-steps (A parity starts at set0, ends ready for set0)
#define GROUP8(vb, cb)                                                        \
    CSTEP(sA0, sB0, sA1, sB1, vb[0], (cb) + 0)                                \
    CSTEP(sA1, sB1, sA0, sB0, vb[1], (cb) + 1)                                \
    CSTEP(sA0, sB0, sA1, sB1, vb[2], (cb) + 2)                                \
    CSTEP(sA1, sB1, sA0, sB0, vb[3], (cb) + 3)                                \
    CSTEP(sA0, sB0, sA1, sB1, vb[4], (cb) + 4)                                \
    CSTEP(sA1, sB1, sA0, sB0, vb[5], (cb) + 5)                                \
    CSTEP(sA0, sB0, sA1, sB1, vb[6], (cb) + 6)                                \
    CSTEP(sA1, sB1, sA0, sB0, vb[7], (cb) + 7)

#define EXTRACT(pm_, gbase_)                                                  \
    {                                                                         \
        unsigned long long pm = (pm_);                                        \
        while (pm) {                                                          \
            int j = __ffsll(pm) - 1;                                          \
            pm &= pm - 1;                                                     \
            float s = sc[orow * 64 + ((j + 4 * orow) & 63)];                  \
            if (s > wv) {                                                     \
                int gj = (gbase_) + j;                                        \
                _Pragma("unroll")                                             \
                for (int s2 = 0; s2 < Kz; ++s2) {                             \
                    bool hit = (s2 == wslot);                                 \
                    tv[s2] = hit ? s : tv[s2];                                \
                    ti[s2] = hit ? gj : ti[s2];                               \
                }                                                             \
                wv = tv[0]; wslot = 0;                                        \
                _Pragma("unroll")                                             \
                for (int s2 = 1; s2 < Kz; ++s2)                               \
                    if (tv[s2] < wv) { wv = tv[s2]; wslot = s2; }             \
            }                                                                 \
        }                                                                     \
    }

#pragma unroll 1
    for (int kp = 0; kp < Nz / 256; ++kp) {
        const int key = kp * 256 + tid;
        const float* bp = xb + key;

        float acc[32];
#pragma unroll
        for (int q = 0; q < 32; ++q) acc[q] = 0.f;

        // B prefetch: group 0 (c = 0..7)
        float vbE[8], vbO[8];
#pragma unroll
        for (int i = 0; i < 8; ++i) vbE[i] = bp[(size_t)i * Nz];

#pragma unroll 1
        for (int gp = 0; gp < 8; ++gp) {       // 2 groups of 8 c per iter
            {   // issue loads for group 2gp+1
                const float* bg = bp + ((size_t)(2 * gp + 1) << 3) * Nz;
#pragma unroll
                for (int i = 0; i < 8; ++i) vbO[i] = bg[(size_t)i * Nz];
            }
            GROUP8(vbE, gp * 16)
            {   // issue loads for group 2gp+2 (wrapped at the end; harmless)
                const int gn = (2 * gp + 2) & 15;
                const float* bg = bp + ((size_t)gn << 3) * Nz;
#pragma unroll
                for (int i = 0; i < 8; ++i) vbE[i] = bg[(size_t)i * Nz];
            }
            GROUP8(vbO, gp * 16 + 8)
        }

        // ---- selection: 4 sub-phases of 64 keys over the 8KB sc tile ----
        const float xxk = xxg[b * Nz + key];
#pragma unroll
        for (int sp = 0; sp < 4; ++sp) {
            if (wid == sp) {
#pragma unroll
                for (int q = 0; q < 32; ++q)
                    sc[q * 64 + ((lane + 4 * q) & 63)] = 2.f * acc[q] - xxk;
            }
            __syncthreads();

            float wvb = __shfl(wv, lane & 7);
            unsigned m = 0;
#pragma unroll
            for (int g = 0; g < 2; ++g) {
                int col = part * 8 + g * 4;
                float4 v = *(const float4*)&sc[srow * 64 + ((col + 4 * srow) & 63)];
                m |= (unsigned)(v.x > wvb) << (4 * g + 0);
                m |= (unsigned)(v.y > wvb) << (4 * g + 1);
                m |= (unsigned)(v.z > wvb) << (4 * g + 2);
                m |= (unsigned)(v.w > wvb) << (4 * g + 3);
            }
            unsigned long long f = (unsigned long long)m << (8 * part);
            f |= __shfl_xor(f, 8);
            f |= __shfl_xor(f, 16);
            f |= __shfl_xor(f, 32);
            if (lane < 8) { EXTRACT(f, kp * 256 + sp * 64); }
            __syncthreads();
        }
    }

    if (lane < 8) {
        size_t base = ((size_t)b * Nz + q0 + orow) * Kz;
#pragma unroll
        for (int s = 0; s < Kz; ++s) idxout[base + s] = ti[s];
    }
#undef CSTEP
#undef GROUP8
#undef EXTRACT
}

// ---------------------------------------------------------------------------
// Kernel 3: Y[p][o'] (unchanged)
// ---------------------------------------------------------------------------
__global__ __launch_bounds__(256) void feat_kernel(const float* __restrict__ x,
                                                   const float* __restrict__ W,
                                                   const float* __restrict__ bias,
                                                   float* __restrict__ Y) {
    const int gp0 = blockIdx.x * 64;         // global point index (b*N+n)
    const int b   = gp0 >> 13;
    const int n0  = gp0 & (Nz - 1);
    const int o0  = blockIdx.y * 64;

    __shared__ __align__(16) float xt[128 * 64];   // [c][p]
    __shared__ __align__(16) float wt[128 * 64];   // [c][o']

    const int tid = threadIdx.x;
    const int tx  = tid & 15;
    const int ty  = tid >> 4;

    {
        int li = tid & 63;
        int c0 = tid >> 6;
        const float* xbp = x + (size_t)b * Cz * Nz + n0;
#pragma unroll
        for (int rep = 0; rep < 32; ++rep) {
            int c = c0 + rep * 4;
            xt[c * 64 + li] = xbp[(size_t)c * Nz + li];
        }
    }
    {
        int lo = tid & 63;
        int c0 = tid >> 6;
        int oo = o0 + lo;
#pragma unroll
        for (int rep = 0; rep < 32; ++rep) {
            int c = c0 + rep * 4;
            float w;
            if (oo < 128) w = W[oo * 256 + c] + W[oo * 256 + 128 + c];
            else          w = W[(oo - 128) * 256 + 128 + c];
            wt[c * 64 + lo] = w;
        }
    }
    __syncthreads();

    float acc[4][4];
#pragma unroll
    for (int di = 0; di < 4; ++di)
#pragma unroll
        for (int dj = 0; dj < 4; ++dj) acc[di][dj] = 0.f;

    const int aoff = ty * 4;
    const int boff = tx * 4;
#pragma unroll 8
    for (int c = 0; c < 128; ++c) {
        float4 a  = *(const float4*)&xt[c * 64 + aoff];
        float4 ww = *(const float4*)&wt[c * 64 + boff];
        float av[4] = {a.x, a.y, a.z, a.w};
        float wvv[4] = {ww.x, ww.y, ww.z, ww.w};
#pragma unroll
        for (int di = 0; di < 4; ++di)
#pragma unroll
            for (int dj = 0; dj < 4; ++dj)
                acc[di][dj] = fmaf(av[di], wvv[dj], acc[di][dj]);
    }

    float4 bv = make_float4(0.f, 0.f, 0.f, 0.f);
    if (o0 < 128) bv = *(const float4*)&bias[o0 + tx * 4];
#pragma unroll
    for (int di = 0; di < 4; ++di) {
        float4 r;
        r.x = acc[di][0] + bv.x;
        r.y = acc[di][1] + bv.y;
        r.z = acc[di][2] + bv.z;
        r.w = acc[di][3] + bv.w;
        *(float4*)&Y[(size_t)(gp0 + ty * 4 + di) * 256 + o0 + tx * 4] = r;
    }
}

// ---------------------------------------------------------------------------
// Kernel 4: out[b][o][n] = relu(u[n][o] - min_j v[idx[n][j]][o])  (unchanged)
// ---------------------------------------------------------------------------
__global__ __launch_bounds__(256) void gather_kernel(const int* __restrict__ idxg,
                                                     const float* __restrict__ Y,
                                                     float* __restrict__ out) {
    const int gp0 = blockIdx.x * 64;
    const int b   = gp0 >> 13;
    const int n0  = gp0 & (Nz - 1);

    __shared__ int lidx[64 * 21];
    const int tid = threadIdx.x;
    for (int t = tid; t < 64 * Kz; t += 256) {
        int p = t / Kz, j = t - p * Kz;
        lidx[p * 21 + j] = idxg[(size_t)(gp0 + p) * Kz + j];
    }
    __syncthreads();

    const int p  = tid & 63;
    const int o0 = (tid >> 6) * 32;

    float mn[32];
#pragma unroll
    for (int q = 0; q < 32; ++q) mn[q] = FLT_MAX;

    for (int j = 0; j < Kz; ++j) {
        int m = lidx[p * 21 + j];
        const float4* vr =
            (const float4*)(Y + (size_t)(b * Nz + m) * 256 + 128 + o0);
#pragma unroll
        for (int q = 0; q < 8; ++q) {
            float4 v4 = vr[q];
            mn[4 * q + 0] = fminf(mn[4 * q + 0], v4.x);
            mn[4 * q + 1] = fminf(mn[4 * q + 1], v4.y);
            mn[4 * q + 2] = fminf(mn[4 * q + 2], v4.z);
            mn[4 * q + 3] = fminf(mn[4 * q + 3], v4.w);
        }
    }

    const float4* ur = (const float4*)(Y + (size_t)(gp0 + p) * 256 + o0);
#pragma unroll
    for (int q = 0; q < 8; ++q) {
        float4 u4 = ur[q];
        float r0 = fmaxf(u4.x - mn[4 * q + 0], 0.f);
        float r1 = fmaxf(u4.y - mn[4 * q + 1], 0.f);
        float r2 = fmaxf(u4.z - mn[4 * q + 2], 0.f);
        float r3 = fmaxf(u4.w - mn[4 * q + 3], 0.f);
        size_t ob = ((size_t)b * OUTz + o0 + 4 * q) * Nz + n0 + p;
        out[ob + 0 * Nz] = r0;
        out[ob + 1 * Nz] = r1;
        out[ob + 2 * Nz] = r2;
        out[ob + 3 * Nz] = r3;
    }
}

// ---------------------------------------------------------------------------
extern "C" void kernel_launch(void* const* d_in, const int* in_sizes, int n_in,
                              void* d_out, int out_size, void* d_ws, size_t ws_size,
                              hipStream_t stream) {
    const float* x    = (const float*)d_in[0];
    const float* W    = (const float*)d_in[1];
    const float* bias = (const float*)d_in[2];
    float* out = (float*)d_out;

    char* ws = (char*)d_ws;
    float* xx  = (float*)ws;                       // 128KB  @ 0
    int*   idx = (int*)(ws + (1 << 17));           // 2.62MB @ 128KB
    float* Y   = (float*)(ws + (4 << 20));         // 32MB   @ 4MB

    xx_kernel<<<dim3(Bz * Nz / 256), dim3(256), 0, stream>>>(x, xx);

    knn_kernel<<<dim3(Nz / 32, Bz), dim3(256), 0, stream>>>(x, xx, idx);

    feat_kernel<<<dim3(Bz * Nz / 64, 4), dim3(256), 0, stream>>>(x, W, bias, Y);

    gather_kernel<<<dim3(Bz * Nz / 64), dim3(256), 0, stream>>>(idx, Y, out);
}